// Round 1
// baseline (120.915 us; speedup 1.0000x reference)
//
#include <hip/hip_runtime.h>

// out[b,m,f,t] = sum_c W[m,f,c] * x[b,m,c,t]
// x: [B=256][NM=5][NC=64][T=1024] f32, W: [NM=5][NF=40][NC=64] f32
// out: [B][NM][NF=40][T] f32
//
// Memory-bound (545 MB @ 6.3 TB/s => ~86 us floor; FMA floor 42.7 us).
// One block per (b*NM+m, t-half). 256 threads x 2 t's each (float2 loads).
// W accesses are wave-uniform -> scalar loads (s_load) via scalar cache.

#define B_  256
#define NM_ 5
#define NC_ 64
#define T_  1024
#define NF_ 40

__global__ __launch_bounds__(256) void trca_einsum_kernel(
    const float* __restrict__ x,
    const float* __restrict__ W,
    float* __restrict__ out)
{
    // grid.x = B*NM*2 ; low bit = t-half
    const int tile = blockIdx.x & 1;
    const int bm   = blockIdx.x >> 1;          // b*NM + m
    const int m    = bm % NM_;
    const int t0   = tile * (T_ / 2) + threadIdx.x * 2;

    const float* __restrict__ xp = x + (size_t)bm * NC_ * T_ + t0;   // x[b,m,c,t0], stride T_ per c
    const float* __restrict__ wp = W + (size_t)m * NF_ * NC_;        // W[m,f,c]
    float* __restrict__ op = out + (size_t)bm * NF_ * T_ + t0;       // out[b,m,f,t0], stride T_ per f

    float acc0[NF_], acc1[NF_];
#pragma unroll
    for (int f = 0; f < NF_; ++f) { acc0[f] = 0.0f; acc1[f] = 0.0f; }

#pragma unroll 2
    for (int c = 0; c < NC_; ++c) {
        const float2 xv = *reinterpret_cast<const float2*>(xp + (size_t)c * T_);
#pragma unroll
        for (int f = 0; f < NF_; ++f) {
            const float w = wp[f * NC_ + c];   // wave-uniform -> s_load
            acc0[f] += w * xv.x;
            acc1[f] += w * xv.y;
        }
    }

#pragma unroll
    for (int f = 0; f < NF_; ++f) {
        *reinterpret_cast<float2*>(op + (size_t)f * T_) = make_float2(acc0[f], acc1[f]);
    }
}

extern "C" void kernel_launch(void* const* d_in, const int* in_sizes, int n_in,
                              void* d_out, int out_size, void* d_ws, size_t ws_size,
                              hipStream_t stream)
{
    const float* x = (const float*)d_in[0];
    const float* W = (const float*)d_in[1];
    float* out = (float*)d_out;

    const int grid = B_ * NM_ * 2;   // 2560 blocks
    trca_einsum_kernel<<<grid, 256, 0, stream>>>(x, W, out);
}

// Round 2
// 114.507 us; speedup vs baseline: 1.0560x; 1.0560x over previous
//
#include <hip/hip_runtime.h>

// out[b,m,f,t] = sum_c W[m,f,c] * x[b,m,c,t]
// x: [B=256][NM=5][NC=64][T=1024] f32, W: [NM=5][NF=40][NC=64] f32
// out: [B][NM][NF=40][T] f32
//
// Memory-bound: 545 MB @ ~7.0 TB/s (measured fill-kernel ceiling) => ~78 us.
// R1: explicit 4-deep load prefetch per c-chunk to raise memory-level
// parallelism (R0 was latency-limited at ~4.5 TB/s effective).

#define B_  256
#define NM_ 5
#define NC_ 64
#define T_  1024
#define NF_ 40
#define CCHUNK 4

__global__ __launch_bounds__(256, 4) void trca_einsum_kernel(
    const float* __restrict__ x,
    const float* __restrict__ W,
    float* __restrict__ out)
{
    // grid.x = B*NM*2 ; low bit = t-half
    const int tile = blockIdx.x & 1;
    const int bm   = blockIdx.x >> 1;          // b*NM + m
    const int m    = bm % NM_;
    const int t0   = tile * (T_ / 2) + threadIdx.x * 2;

    const float* __restrict__ xp = x + (size_t)bm * NC_ * T_ + t0;   // stride T_ per c
    const float* __restrict__ wp = W + (size_t)m * NF_ * NC_;        // W[m,f,c]
    float* __restrict__ op = out + (size_t)bm * NF_ * T_ + t0;       // stride T_ per f

    float acc0[NF_], acc1[NF_];
#pragma unroll
    for (int f = 0; f < NF_; ++f) { acc0[f] = 0.0f; acc1[f] = 0.0f; }

    for (int cc = 0; cc < NC_; cc += CCHUNK) {
        // Issue CCHUNK loads back-to-back (static indices -> registers).
        float2 xv[CCHUNK];
#pragma unroll
        for (int i = 0; i < CCHUNK; ++i) {
            xv[i] = *reinterpret_cast<const float2*>(xp + (size_t)(cc + i) * T_);
        }
#pragma unroll
        for (int i = 0; i < CCHUNK; ++i) {
#pragma unroll
            for (int f = 0; f < NF_; ++f) {
                const float w = wp[f * NC_ + cc + i];   // wave-uniform -> s_load
                acc0[f] += w * xv[i].x;
                acc1[f] += w * xv[i].y;
            }
        }
    }

#pragma unroll
    for (int f = 0; f < NF_; ++f) {
        __builtin_nontemporal_store(acc0[f], op + (size_t)f * T_);
        __builtin_nontemporal_store(acc1[f], op + (size_t)f * T_ + 1);
    }
}

extern "C" void kernel_launch(void* const* d_in, const int* in_sizes, int n_in,
                              void* d_out, int out_size, void* d_ws, size_t ws_size,
                              hipStream_t stream)
{
    const float* x = (const float*)d_in[0];
    const float* W = (const float*)d_in[1];
    float* out = (float*)d_out;

    const int grid = B_ * NM_ * 2;   // 2560 blocks
    trca_einsum_kernel<<<grid, 256, 0, stream>>>(x, W, out);
}